// Round 7
// baseline (50.569 us; speedup 1.0000x reference)
//
#include <hip/hip_runtime.h>
#include <hip/hip_bf16.h>

#define CIN   128
#define HH    64
#define WW    64
#define COUT  256
#define HO    64
#define WO    64
#define NTAP  9
#define KTOT  (CIN*NTAP)   /* 1152 */
#define BK    32
#define NSTEP (KTOT/BK)    /* 36 */
#define NB    8
#define CROW  272          /* cols row stride in bytes (256 data + 16 pad) */
#define CBUF  (WO*CROW)    /* one cols buffer: 17408 B */

typedef __attribute__((ext_vector_type(8))) short bf16x8;
typedef __attribute__((ext_vector_type(4))) short bf16x4;
typedef __attribute__((ext_vector_type(4))) float f32x4;

struct __align__(16) TapEntry {
  int   i00, i01, i10, i11;    // BYTE offsets into xt's per-image slice
  float w00, w01, w10, w11;
};

static __device__ __forceinline__ ushort f2bf(float v) {
  unsigned u = __float_as_uint(v);
  unsigned rnd = 0x7fffu + ((u >> 16) & 1u);
  return (ushort)((u + rnd) >> 16);
}
static __device__ __forceinline__ float bf2f(short s) {
  return __uint_as_float(((unsigned)(unsigned short)s) << 16);
}

static __device__ __forceinline__ bf16x8 combine4(const bf16x8 c00, const bf16x8 c01,
                                                  const bf16x8 c10, const bf16x8 c11,
                                                  const f32x4 w) {
  bf16x8 r;
  #pragma unroll
  for (int j = 0; j < 8; ++j) {
    const float v = w.x * bf2f(c00[j]) + w.y * bf2f(c01[j])
                  + w.z * bf2f(c10[j]) + w.w * bf2f(c11[j]);
    r[j] = (short)f2bf(v);
  }
  return r;
}

// ---- prep: x NCHW f32 -> xt NHWC bf16  +  weight repack to wbt ----
// wbt element (s, c16, lane=q*16+r, j) = w[co=c16*16+r][ci=(s&3)*32+q*8+j][tap=s>>2]
__global__ __launch_bounds__(256) void prep(const float* __restrict__ x,
                                            const float* __restrict__ w,
                                            ushort* __restrict__ xt,
                                            ushort* __restrict__ wbt) {
  const int blk = blockIdx.x;
  const int tid = threadIdx.x;
  if (blk < NB * HH) {
    const int b = blk >> 6, y = blk & 63;
    const int px = tid & 63, c8 = tid >> 6;
    const float* src = x + (size_t)b * CIN * HH * WW + y * WW + px;
    ushort* dst = xt + (((size_t)(b * HH + y) * WW) + px) * CIN;
    #pragma unroll
    for (int cc = 0; cc < 4; ++cc) {
      const int c0 = cc * 32 + c8 * 8;
      bf16x8 v;
      #pragma unroll
      for (int j = 0; j < 8; ++j)
        v[j] = (short)f2bf(src[(size_t)(c0 + j) * (HH * WW)]);
      *reinterpret_cast<bf16x8*>(dst + c0) = v;
    }
  } else {
    const int h = (blk - NB * HH) * 256 + tid;
    const int s   = h >> 10;
    const int c16 = (h >> 6) & 15;
    const int l   = h & 63;
    const int q   = l >> 4;
    const int r   = l & 15;
    const int co  = c16 * 16 + r;
    const int tap = s >> 2;
    const int ci0 = (s & 3) * 32 + q * 8;
    bf16x8 o;
    #pragma unroll
    for (int j = 0; j < 8; ++j)
      o[j] = (short)f2bf(w[(size_t)(co * CIN + ci0 + j) * NTAP + tap]);
    *reinterpret_cast<bf16x8*>(wbt + (size_t)h * 8) = o;
  }
}

// ---- main: pipelined coalesced gather + implicit GEMM ----
__global__ __launch_bounds__(256, 2)
void dcn6(const ushort* __restrict__ xt, const float* __restrict__ off,
          const ushort* __restrict__ wbt, float* __restrict__ out)
{
  __shared__ TapEntry taps[NTAP * WO];                 // 18432 B
  __shared__ __align__(16) char colsB[2 * CBUF];       // 2 x 17408 B

  const int tid = threadIdx.x;
  // b in low 3 bits: all 64 blocks of one image land on one XCD (L2 locality)
  const int b  = blockIdx.x & 7;
  const int ho = blockIdx.x >> 3;

  for (int e = tid; e < NTAP * WO; e += 256) {
    const int k  = e >> 6;
    const int wo = e & 63;
    const float* op = off + (((size_t)(b * 18 + 2 * k) * HO + ho) * WO + wo);
    const float dy = op[0];
    const float dx = op[HO * WO];
    const float py  = (float)(ho - 1 + (k / 3)) + dy;
    const float pxf = (float)(wo - 1 + (k % 3)) + dx;
    const float y0f = floorf(py), x0f = floorf(pxf);
    const float fy = py - y0f, fx = pxf - x0f;
    const int y0 = (int)y0f, x0 = (int)x0f;
    const int y1 = y0 + 1,  x1 = x0 + 1;
    const bool vy0 = (unsigned)y0 < HH, vy1 = (unsigned)y1 < HH;
    const bool vx0 = (unsigned)x0 < WW, vx1 = (unsigned)x1 < WW;
    const int cy0 = min(max(y0, 0), HH - 1), cy1 = min(max(y1, 0), HH - 1);
    const int cx0 = min(max(x0, 0), WW - 1), cx1 = min(max(x1, 0), WW - 1);
    TapEntry t;
    t.i00 = (cy0 * WW + cx0) << 8;  t.i01 = (cy0 * WW + cx1) << 8;  // *CIN*2B
    t.i10 = (cy1 * WW + cx0) << 8;  t.i11 = (cy1 * WW + cx1) << 8;
    const float gy = 1.f - fy, gx = 1.f - fx;
    t.w00 = (vy0 && vx0) ? gy * gx : 0.f;
    t.w01 = (vy0 && vx1) ? gy * fx : 0.f;
    t.w10 = (vy1 && vx0) ? fy * gx : 0.f;
    t.w11 = (vy1 && vx1) ? fy * fx : 0.f;
    taps[e] = t;
  }

  const int lane = tid & 63;
  const int grp  = tid >> 6;   // wave id: px-group (producer) AND co-group (consumer)
  const int l15  = lane & 15;
  const int q    = lane >> 4;
  const int g    = q;          // gather: pixel-subindex within quad
  const int s16b = l15 * 16;   // gather: byte offset of 16B chunk in 256B row

  f32x4 acc[4][4];
  #pragma unroll
  for (int m = 0; m < 4; ++m)
    #pragma unroll
    for (int n = 0; n < 4; ++n)
      acc[m][n] = 0.f;

  const char* xb = reinterpret_cast<const char*>(xt)
                 + (size_t)b * (HH * WW * CIN * 2) + s16b;

  __syncthreads();   // taps ready

  // pipeline registers: corners for the NEXT tap (issued early, combined late)
  bf16x8 c00[4], c01[4], c10[4], c11[4];
  f32x4  tw[4];

  // ---- prologue: gather tap 0 -> buf0 ----
  #pragma unroll
  for (int pq = 0; pq < 4; ++pq) {
    const int px = (grp << 4) + (pq << 2) + g;
    const TapEntry te = taps[px];
    c00[pq] = *reinterpret_cast<const bf16x8*>(xb + te.i00);
    c01[pq] = *reinterpret_cast<const bf16x8*>(xb + te.i01);
    c10[pq] = *reinterpret_cast<const bf16x8*>(xb + te.i10);
    c11[pq] = *reinterpret_cast<const bf16x8*>(xb + te.i11);
    tw[pq]  = f32x4{te.w00, te.w01, te.w10, te.w11};
  }
  #pragma unroll
  for (int pq = 0; pq < 4; ++pq) {
    const int px = (grp << 4) + (pq << 2) + g;
    const bf16x8 hv = combine4(c00[pq], c01[pq], c10[pq], c11[pq], tw[pq]);
    *reinterpret_cast<bf16x8*>(colsB + px * CROW + s16b) = hv;
  }
  __syncthreads();   // buf0 ready

  #pragma unroll 1
  for (int tap = 0; tap < NTAP; ++tap) {
    const int cur = tap & 1;
    const char* rbuf = colsB + cur * CBUF;
    char*       wbuf = colsB + (cur ^ 1) * CBUF;
    const bool  more = (tap + 1) < NTAP;

    // A-fragment base for this tap: s = tap*4 + kk
    const ushort* aBase = wbt + ((size_t)((tap * 4 * 16 + grp * 4) * 64 + lane)) * 8;
    #define ALOAD(kk, m) (*reinterpret_cast<const bf16x8*>(aBase + ((kk) * 16 + (m)) * 64 * 8))

    // prefetch A for kk0, kk1
    bf16x8 a0[4], a1[4];
    #pragma unroll
    for (int m = 0; m < 4; ++m) { a0[m] = ALOAD(0, m); a1[m] = ALOAD(1, m); }

    // issue next tap's 16 corner loads (consumed after the MFMA phase)
    if (more) {
      #pragma unroll
      for (int pq = 0; pq < 4; ++pq) {
        const int px = (grp << 4) + (pq << 2) + g;
        const TapEntry te = taps[(tap + 1) * WO + px];
        c00[pq] = *reinterpret_cast<const bf16x8*>(xb + te.i00);
        c01[pq] = *reinterpret_cast<const bf16x8*>(xb + te.i01);
        c10[pq] = *reinterpret_cast<const bf16x8*>(xb + te.i10);
        c11[pq] = *reinterpret_cast<const bf16x8*>(xb + te.i11);
        tw[pq]  = f32x4{te.w00, te.w01, te.w10, te.w11};
      }
    }

    bf16x8 bb[4];
    #define BLOAD(kk) do { \
      _Pragma("unroll") \
      for (int n = 0; n < 4; ++n) \
        bb[n] = *reinterpret_cast<const bf16x8*>( \
            rbuf + (n * 16 + l15) * CROW + (kk) * 64 + q * 16); \
    } while (0)
    #define MFMA16(A) do { \
      _Pragma("unroll") \
      for (int m = 0; m < 4; ++m) \
        _Pragma("unroll") \
        for (int n = 0; n < 4; ++n) \
          acc[m][n] = __builtin_amdgcn_mfma_f32_16x16x32_bf16( \
              (A)[m], bb[n], acc[m][n], 0, 0, 0); \
    } while (0)

    // kk = 0
    BLOAD(0); MFMA16(a0);
    #pragma unroll
    for (int m = 0; m < 4; ++m) a0[m] = ALOAD(2, m);   // prefetch kk2
    // kk = 1
    BLOAD(1); MFMA16(a1);
    #pragma unroll
    for (int m = 0; m < 4; ++m) a1[m] = ALOAD(3, m);   // prefetch kk3
    // kk = 2
    BLOAD(2); MFMA16(a0);
    // kk = 3
    BLOAD(3); MFMA16(a1);

    // combine next tap's corners (loads have had the whole MFMA phase) + write
    if (more) {
      #pragma unroll
      for (int pq = 0; pq < 4; ++pq) {
        const int px = (grp << 4) + (pq << 2) + g;
        const bf16x8 hv = combine4(c00[pq], c01[pq], c10[pq], c11[pq], tw[pq]);
        *reinterpret_cast<bf16x8*>(wbuf + px * CROW + s16b) = hv;
      }
    }
    __syncthreads();
    #undef ALOAD
    #undef BLOAD
    #undef MFMA16
  }

  // ---- epilogue: D row(co) = q*4+r (+m*16), col(wo) = l15 (+n*16) ----
  #pragma unroll
  for (int m = 0; m < 4; ++m)
    #pragma unroll
    for (int n = 0; n < 4; ++n)
      #pragma unroll
      for (int r = 0; r < 4; ++r) {
        const int co = grp * 64 + m * 16 + q * 4 + r;
        const int wo = n * 16 + l15;
        out[(((size_t)b * COUT + co) * HO + ho) * WO + wo] = acc[m][n][r];
      }
}

// ---- fallback (ws too small): round-1 f32-gather path ----
__global__ __launch_bounds__(256, 2)
void dcn_f32(const float* __restrict__ x, const float* __restrict__ off,
             const float* __restrict__ wgt, float* __restrict__ out)
{
  __shared__ TapEntry taps[NTAP * WO];
  __shared__ __align__(16) ushort colsf[WO * 40];
  const int tid = threadIdx.x;
  const int b  = blockIdx.x & 7;
  const int ho = blockIdx.x >> 3;
  for (int e = tid; e < NTAP * WO; e += 256) {
    const int k  = e >> 6;
    const int wo = e & 63;
    const float* op = off + (((size_t)(b * 18 + 2 * k) * HO + ho) * WO + wo);
    const float dy = op[0];
    const float dx = op[HO * WO];
    const float py  = (float)(ho - 1 + (k / 3)) + dy;
    const float pxf = (float)(wo - 1 + (k % 3)) + dx;
    const float y0f = floorf(py), x0f = floorf(pxf);
    const float fy = py - y0f, fx = pxf - x0f;
    const int y0 = (int)y0f, x0 = (int)x0f;
    const int y1 = y0 + 1,  x1 = x0 + 1;
    const bool vy0 = (unsigned)y0 < HH, vy1 = (unsigned)y1 < HH;
    const bool vx0 = (unsigned)x0 < WW, vx1 = (unsigned)x1 < WW;
    const int cy0 = min(max(y0, 0), HH - 1), cy1 = min(max(y1, 0), HH - 1);
    const int cx0 = min(max(x0, 0), WW - 1), cx1 = min(max(x1, 0), WW - 1);
    TapEntry t;
    t.i00 = cy0 * WW + cx0; t.i01 = cy0 * WW + cx1;
    t.i10 = cy1 * WW + cx0; t.i11 = cy1 * WW + cx1;
    const float gy = 1.f - fy, gx = 1.f - fx;
    t.w00 = (vy0 && vx0) ? gy * gx : 0.f;
    t.w01 = (vy0 && vx1) ? gy * fx : 0.f;
    t.w10 = (vy1 && vx0) ? fy * gx : 0.f;
    t.w11 = (vy1 && vx1) ? fy * fx : 0.f;
    taps[e] = t;
  }
  const int px = tid & 63, grp = tid >> 6, lane = tid & 63;
  const int l15 = lane & 15, q = lane >> 4;
  f32x4 acc[4][4];
  #pragma unroll
  for (int m = 0; m < 4; ++m)
    #pragma unroll
    for (int n = 0; n < 4; ++n) acc[m][n] = 0.f;
  const float* xb = x + (size_t)b * CIN * HH * WW;
  __syncthreads();
  for (int tap = 0; tap < NTAP; ++tap) {
    const TapEntry e = taps[tap * WO + px];
    for (int cb = 0; cb < 4; ++cb) {
      __syncthreads();
      {
        const float* xp = xb + (size_t)(cb * 32 + grp * 8) * (HH * WW);
        bf16x8 hv;
        #pragma unroll
        for (int j = 0; j < 8; ++j) {
          const float* p = xp + j * (HH * WW);
          const float v = e.w00 * p[e.i00] + e.w01 * p[e.i01]
                        + e.w10 * p[e.i10] + e.w11 * p[e.i11];
          hv[j] = (short)f2bf(v);
        }
        *reinterpret_cast<bf16x8*>(
            reinterpret_cast<char*>(colsf) + px * 80 + grp * 16) = hv;
      }
      __syncthreads();
      bf16x8 a[4], bbf[4];
      #pragma unroll
      for (int m = 0; m < 4; ++m) {
        const int co = grp * 64 + m * 16 + l15;
        bf16x8 t;
        #pragma unroll
        for (int j = 0; j < 8; ++j)
          t[j] = (short)f2bf(wgt[(size_t)(co * CIN + cb * 32 + q * 8 + j) * NTAP + tap]);
        a[m] = t;
      }
      #pragma unroll
      for (int n = 0; n < 4; ++n)
        bbf[n] = *reinterpret_cast<const bf16x8*>(
            reinterpret_cast<const char*>(colsf) + (n * 16 + l15) * 80 + q * 16);
      #pragma unroll
      for (int m = 0; m < 4; ++m)
        #pragma unroll
        for (int n = 0; n < 4; ++n)
          acc[m][n] = __builtin_amdgcn_mfma_f32_16x16x32_bf16(
              a[m], bbf[n], acc[m][n], 0, 0, 0);
    }
  }
  const int wco = grp * 64;
  #pragma unroll
  for (int m = 0; m < 4; ++m)
    #pragma unroll
    for (int n = 0; n < 4; ++n)
      #pragma unroll
      for (int r = 0; r < 4; ++r) {
        const int co = wco + m * 16 + q * 4 + r;
        const int wo = n * 16 + l15;
        out[(((size_t)b * COUT + co) * HO + ho) * WO + wo] = acc[m][n][r];
      }
}

extern "C" void kernel_launch(void* const* d_in, const int* in_sizes, int n_in,
                              void* d_out, int out_size, void* d_ws, size_t ws_size,
                              hipStream_t stream) {
  const float* x   = (const float*)d_in[0];   // [8,128,64,64]
  const float* off = (const float*)d_in[1];   // [8,18,64,64]
  const float* wgt = (const float*)d_in[2];   // [256,128,3,3]
  float* out = (float*)d_out;                 // [8,256,64,64]

  const size_t xt_bytes = (size_t)NB * HH * WW * CIN * sizeof(ushort);   // 8 MiB
  const size_t wb_bytes = (size_t)NSTEP * COUT * BK * sizeof(ushort);    // 576 KiB
  if (ws_size >= xt_bytes + wb_bytes) {
    ushort* xtp  = (ushort*)d_ws;
    ushort* wbtp = (ushort*)((char*)d_ws + xt_bytes);
    const int wchunks = NSTEP * COUT * BK / 8;        // 36864 16B chunks
    const int wblocks = wchunks / 256;                // 144
    prep<<<NB * HH + wblocks, 256, 0, stream>>>(x, wgt, xtp, wbtp);
    dcn6<<<NB * HO, 256, 0, stream>>>(xtp, off, wbtp, out);
  } else {
    dcn_f32<<<NB * HO, 256, 0, stream>>>(x, off, wgt, out);
  }
}